// Round 12
// baseline (274.491 us; speedup 1.0000x reference)
//
#include <hip/hip_runtime.h>

#define BB 16384
#define KK 64
#define DD 128
#define SEG 256          // rows per covariance work-item (2x128-row stages)
#define MAXITEMS 128     // sum_k ceil(cnt_k/SEG) <= 64 + 63 = 127
#define NRB 4            // reduce slabs per cluster
#define RSLAB 4096       // elements per reduce slab
#define NBLK 256         // k_main grid (1 block/CU -> co-resident barrier OK)

typedef __attribute__((ext_vector_type(8))) short bf16x8;
typedef __attribute__((ext_vector_type(4))) float f32x4;

__device__ __forceinline__ unsigned int packbf2(float a, float b) {
    unsigned ua = __float_as_uint(a);
    unsigned ub = __float_as_uint(b);
    ua = (ua + 0x7FFFu + ((ua >> 16) & 1u)) >> 16;   // RNE f32->bf16
    ub = (ub + 0x7FFFu + ((ub >> 16) & 1u)) >> 16;
    return ua | (ub << 16);
}

// ---------------------------------------------------------------------------
// K1: tiled GEMM. Block = 64 rows x 64 clusters, K=128.
// dist = |x|^2 - 2 x.c + |c|^2 ; |x|^2 cancels in softmax AND argmin.
// Emits per-block cluster histogram bhist[b][k]; zeroes barrier counters.
// ---------------------------------------------------------------------------
__global__ __launch_bounds__(256) void k_rows(
    const float* __restrict__ x, const float* __restrict__ centers,
    float* __restrict__ log_resp, int* __restrict__ assign,
    int* __restrict__ bhist, int* __restrict__ counters)
{
    __shared__ float xs[64][132];    // X tile, +4 pad
    __shared__ float ct[DD][66];     // centers transposed [d][k]
    __shared__ float cn2[KK];
    __shared__ int   lh[KK];

    const int tid = threadIdx.x;
    const int row0 = blockIdx.x * 64;

    if (blockIdx.x == 0 && tid < 2) counters[tid] = 0;   // bar1, fincnt
    if (tid < KK) lh[tid] = 0;

    for (int g = tid; g < 64 * 32; g += 256) {
        int r = g >> 5, c4 = g & 31;
        float4 v = ((const float4*)(x + (size_t)(row0 + r) * DD))[c4];
        *(float4*)&xs[r][c4 * 4] = v;
    }
    for (int g = tid; g < KK * 32; g += 256) {
        int k = g >> 5, c4 = g & 31;
        float4 v = ((const float4*)(centers + (size_t)k * DD))[c4];
        ct[c4 * 4 + 0][k] = v.x;
        ct[c4 * 4 + 1][k] = v.y;
        ct[c4 * 4 + 2][k] = v.z;
        ct[c4 * 4 + 3][k] = v.w;
    }
    __syncthreads();
    if (tid < KK) {
        float s = 0.f;
        for (int d = 0; d < DD; ++d) { float c = ct[d][tid]; s = fmaf(c, c, s); }
        cn2[tid] = s;
    }
    __syncthreads();

    const int tr = tid >> 5;
    const int tc = tid & 31;
    const int k0 = tc * 2, k1 = k0 + 1;

    float acc0[8], acc1[8];
    #pragma unroll
    for (int i = 0; i < 8; ++i) { acc0[i] = 0.f; acc1[i] = 0.f; }

    for (int d = 0; d < DD; d += 4) {
        float2 b0 = *(const float2*)&ct[d + 0][k0];
        float2 b1 = *(const float2*)&ct[d + 1][k0];
        float2 b2 = *(const float2*)&ct[d + 2][k0];
        float2 b3 = *(const float2*)&ct[d + 3][k0];
        #pragma unroll
        for (int i = 0; i < 8; ++i) {
            float4 a = *(const float4*)&xs[tr * 8 + i][d];
            acc0[i] = fmaf(a.x, b0.x, acc0[i]);
            acc1[i] = fmaf(a.x, b0.y, acc1[i]);
            acc0[i] = fmaf(a.y, b1.x, acc0[i]);
            acc1[i] = fmaf(a.y, b1.y, acc1[i]);
            acc0[i] = fmaf(a.z, b2.x, acc0[i]);
            acc1[i] = fmaf(a.z, b2.y, acc1[i]);
            acc0[i] = fmaf(a.w, b3.x, acc0[i]);
            acc1[i] = fmaf(a.w, b3.y, acc1[i]);
        }
    }

    const float cn0 = 0.5f * cn2[k0], cn1 = 0.5f * cn2[k1];
    #pragma unroll
    for (int i = 0; i < 8; ++i) {
        int row = row0 + tr * 8 + i;
        float v0 = acc0[i] - cn0;
        float v1 = acc1[i] - cn1;
        float m; int idx;
        if (v1 > v0) { m = v1; idx = k1; } else { m = v0; idx = k0; }
        #pragma unroll
        for (int off = 1; off < 32; off <<= 1) {
            float ov = __shfl_xor(m, off);
            int   oi = __shfl_xor(idx, off);
            if (ov > m || (ov == m && oi < idx)) { m = ov; idx = oi; }
        }
        float s = expf(v0 - m) + expf(v1 - m);
        #pragma unroll
        for (int off = 1; off < 32; off <<= 1) s += __shfl_xor(s, off);
        float ls = logf(s);
        float lr0 = fmaxf(v0 - m - ls, -18.4206807f);  // log(1e-8)
        float lr1 = fmaxf(v1 - m - ls, -18.4206807f);
        *(float2*)&log_resp[(size_t)row * KK + k0] = make_float2(lr0, lr1);
        if (tc == 0) {
            assign[row] = idx;
            atomicAdd(&lh[idx], 1);
        }
    }
    __syncthreads();
    if (tid < KK) bhist[blockIdx.x * KK + tid] = lh[tid];   // coalesced 256B
}

// ---------------------------------------------------------------------------
// K2 (grid = 256, regular launch): B' redundant metadata from bhist; C gather
// member rows via ballot-compaction scan of assign (no sorted array) + MFMA
// Sxx -> part/emp_part; software grid barrier (threadfence release + counter
// + s_sleep spin + acquire — the R11-validated agent-scope pattern); D
// streaming reduce + centered covariance + spart/last-block scalar writeout.
// ---------------------------------------------------------------------------
__global__ __launch_bounds__(256) void k_main(
    const float* __restrict__ x, const int* __restrict__ assign,
    const int* __restrict__ bhist, const float* __restrict__ centers,
    float* __restrict__ part, float* __restrict__ emp_part,
    float2* __restrict__ spart, int* __restrict__ counters,
    float* __restrict__ outscalars)
{
    __shared__ __align__(16) char smem[65536];
    unsigned int (*XT)[68] = (unsigned int (*)[68])smem;        // C: 34816 B
    int* rows_s = (int*)(smem + 34816);                         // C: 1024 B
    float (*red)[RSLAB] = (float (*)[RSLAB])smem;               // D: 65536 B

    __shared__ int ph_tot[4][KK];
    __shared__ int cnt_s[KK], ist_s[KK], ien_s[KK];
    __shared__ int wtot[4];
    __shared__ int myk_s, myseg_s;

    const int tid = threadIdx.x;
    const int b = blockIdx.x;
    const int w = tid >> 6, lane = tid & 63;
    int* bar1 = counters;
    int* fincnt = counters + 1;

    // ---------------- Phase B': metadata (redundant per block) ----------------
    {
        const int t = tid & 63, q = tid >> 6;
        int tot = 0;
        for (int bb = q * 64; bb < q * 64 + 64; ++bb)
            tot += bhist[bb * KK + t];               // coalesced across lanes
        ph_tot[q][t] = tot;
    }
    __syncthreads();
    if (tid < KK)
        cnt_s[tid] = ph_tot[0][tid] + ph_tot[1][tid] + ph_tot[2][tid] + ph_tot[3][tid];
    __syncthreads();
    if (tid == 0) {
        int ic = 0;
        myk_s = -1;
        for (int k = 0; k < KK; ++k) {
            ist_s[k] = ic;
            int ns = (cnt_s[k] + SEG - 1) / SEG;
            if (b >= ic && b < ic + ns) { myk_s = k; myseg_s = b - ic; }
            ic += ns;
            ien_s[k] = ic;
        }
    }
    __syncthreads();

    // ---------------- Phase C: per-item Sxx via MFMA ----------------
    if (myk_s >= 0) {
        const int kC = myk_s;
        const int lo = myseg_s * SEG;
        const int hi = min(lo + SEG, cnt_s[kC]);
        const int len = hi - lo;

        // gather my rows: ordered ballot-compaction scan of assign
        {
            int running = 0;
            for (int c = 0; c < BB / 256; ++c) {     // 64 chunks
                if (running >= hi) break;            // uniform
                int a = assign[c * 256 + tid];
                bool m = (a == kC);
                unsigned long long bal = __ballot(m);
                if (lane == 0) wtot[w] = __popcll(bal);
                __syncthreads();
                int woff = 0;
                #pragma unroll
                for (int j = 0; j < 4; ++j) if (j < w) woff += wtot[j];
                int ctot = wtot[0] + wtot[1] + wtot[2] + wtot[3];
                if (m) {
                    int rank = __popcll(bal & ((1ull << lane) - 1ull));
                    int pos = running + woff + rank;
                    if (pos >= lo && pos < hi) rows_s[pos - lo] = c * 256 + tid;
                }
                running += ctot;
                __syncthreads();                     // wtot WAR
            }
        }

        const int c4 = lane & 15, q = lane >> 4;
        f32x4 acc[2][8];
        #pragma unroll
        for (int h = 0; h < 2; ++h)
            #pragma unroll
            for (int nt = 0; nt < 8; ++nt)
                acc[h][nt] = (f32x4){0.f, 0.f, 0.f, 0.f};
        float colsum = 0.f;

        for (int half = 0; half < 2; ++half) {
            const int hoff = half * 128;
            const int hlen = min(128, len - hoff);   // uniform
            if (hlen <= 0) break;

            __syncthreads();   // WAR on XT (prev half's MFMA reads done)
            // stage: wave w owns dims [w*32, w*32+32); lane owns row pair
            {
                const int r0 = 2 * lane, r1 = 2 * lane + 1;
                const int d0 = w * 32;
                const float* p0 = x + (size_t)rows_s[hoff + (r0 < hlen ? r0 : 0)] * DD + d0;
                const float* p1 = x + (size_t)rows_s[hoff + (r1 < hlen ? r1 : 0)] * DD + d0;
                #pragma unroll
                for (int i = 0; i < 8; ++i) {
                    float4 a = make_float4(0.f, 0.f, 0.f, 0.f);
                    float4 bb = make_float4(0.f, 0.f, 0.f, 0.f);
                    if (r0 < hlen) a  = *(const float4*)(p0 + 4 * i);
                    if (r1 < hlen) bb = *(const float4*)(p1 + 4 * i);
                    XT[d0 + 4 * i + 0][lane] = packbf2(a.x, bb.x);
                    XT[d0 + 4 * i + 1][lane] = packbf2(a.y, bb.y);
                    XT[d0 + 4 * i + 2][lane] = packbf2(a.z, bb.z);
                    XT[d0 + 4 * i + 3][lane] = packbf2(a.w, bb.w);
                }
            }
            __syncthreads();

            // column sums (f32 from the bf16 data)
            if (tid < DD) {
                float s = 0.f;
                #pragma unroll
                for (int j4 = 0; j4 < 16; ++j4) {
                    uint4 v = *(const uint4*)&XT[tid][j4 * 4];
                    s += __uint_as_float(v.x << 16) + __uint_as_float(v.x & 0xFFFF0000u);
                    s += __uint_as_float(v.y << 16) + __uint_as_float(v.y & 0xFFFF0000u);
                    s += __uint_as_float(v.z << 16) + __uint_as_float(v.z & 0xFFFF0000u);
                    s += __uint_as_float(v.w << 16) + __uint_as_float(v.w & 0xFFFF0000u);
                }
                colsum += s;
            }

            // MFMA: wave w owns m-tiles {2w, 2w+1} x n-tiles 0..7
            #pragma unroll
            for (int c = 0; c < 4; ++c) {
                const int ku = c * 16 + q * 4;
                bf16x8 a0 = *(const bf16x8*)&XT[(2 * w + 0) * 16 + c4][ku];
                bf16x8 a1 = *(const bf16x8*)&XT[(2 * w + 1) * 16 + c4][ku];
                #pragma unroll
                for (int nt = 0; nt < 8; ++nt) {
                    bf16x8 bb = *(const bf16x8*)&XT[nt * 16 + c4][ku];
                    acc[0][nt] = __builtin_amdgcn_mfma_f32_16x16x32_bf16(a0, bb, acc[0][nt], 0, 0, 0);
                    acc[1][nt] = __builtin_amdgcn_mfma_f32_16x16x32_bf16(a1, bb, acc[1][nt], 0, 0, 0);
                }
            }
        }

        if (tid < DD) emp_part[b * DD + tid] = colsum;

        // C/D layout: col = lane&15, row = quad*4 + reg  [m89/m91 verified]
        float* pb = part + (size_t)b * (DD * DD);
        #pragma unroll
        for (int h = 0; h < 2; ++h) {
            const int m0 = (2 * w + h) * 16 + q * 4;
            #pragma unroll
            for (int nt = 0; nt < 8; ++nt) {
                const int n = nt * 16 + c4;
                pb[(m0 + 0) * DD + n] = acc[h][nt].x;
                pb[(m0 + 1) * DD + n] = acc[h][nt].y;
                pb[(m0 + 2) * DD + n] = acc[h][nt].z;
                pb[(m0 + 3) * DD + n] = acc[h][nt].w;
            }
        }
    }

    // ---------------- software grid barrier ----------------
    __syncthreads();
    if (tid == 0) {
        __threadfence();                              // release part/emp_part
        atomicAdd(bar1, 1);
        while (__hip_atomic_load(bar1, __ATOMIC_ACQUIRE,
                                 __HIP_MEMORY_SCOPE_AGENT) < NBLK)
            __builtin_amdgcn_s_sleep(8);
    }
    __syncthreads();
    __threadfence();                                  // acquire

    // ---------------- Phase D: reduce + covariance + scalars ----------------
    {
        const int kD = b >> 2;
        const int p = b & 3;
        const int i0 = ist_s[kD], i1 = ien_s[kD];
        const float wgt = (float)cnt_s[kD];
        const float inv = 1.0f / (wgt + 1e-7f);

        __shared__ float mu_s[DD], emp_s[DD];
        __shared__ float emp2[2][DD];

        // emp = sum over items of emp_part (2 groups x 2 chains)
        {
            const int dh = tid & 127, hf = tid >> 7;
            float e0 = 0.f, e1 = 0.f;
            int it = i0 + hf;
            for (; it + 2 < i1; it += 4) {
                e0 += emp_part[it * DD + dh];
                e1 += emp_part[(it + 2) * DD + dh];
            }
            if (it < i1) e0 += emp_part[it * DD + dh];
            emp2[hf][dh] = e0 + e1;
        }
        __syncthreads();
        if (tid < DD) {
            float e = emp2[0][tid] + emp2[1][tid];
            emp_s[tid] = e;
            mu_s[tid] = e * inv;
        }

        float4 acc[16];
        #pragma unroll
        for (int c = 0; c < 16; ++c) acc[c] = make_float4(0.f, 0.f, 0.f, 0.f);

        const int base = p * RSLAB;
        for (int it = i0 + w; it < i1; it += 4) {
            const float* pb = part + (size_t)it * (DD * DD) + base;
            #pragma unroll
            for (int c = 0; c < 16; ++c) {
                float4 v = *(const float4*)&pb[c * 256 + lane * 4];
                acc[c].x += v.x; acc[c].y += v.y; acc[c].z += v.z; acc[c].w += v.w;
            }
        }
        __syncthreads();   // XT reads long done; safe to overwrite smem as red
        #pragma unroll
        for (int c = 0; c < 16; ++c)
            *(float4*)&red[w][c * 256 + lane * 4] = acc[c];
        __syncthreads();

        float ds = 0.f, os = 0.f, mm = 0.f;
        #pragma unroll
        for (int jj = 0; jj < 16; ++jj) {
            int el = jj * 256 + tid;               // stride-1 across lanes
            float sx = red[0][el] + red[1][el] + red[2][el] + red[3][el];
            int gel = base + el;
            int d = gel >> 7, e = gel & 127;
            float ctv = sx - mu_s[d] * emp_s[e] - emp_s[d] * mu_s[e]
                      + wgt * mu_s[d] * mu_s[e];
            float v = ctv * inv;
            if (d == e) { float t = v - 1.f; ds += t * t; }
            else        { os += v * v; }
        }
        if (p == 0 && tid < DD) {
            float t = mu_s[tid] - centers[kD * DD + tid];
            mm = t * t;
        }

        #pragma unroll
        for (int off = 32; off > 0; off >>= 1) {
            ds += __shfl_down(ds, off);
            os += __shfl_down(os, off);
            mm += __shfl_down(mm, off);
        }
        __shared__ float rds[4], ros[4], rmm[4];
        __shared__ int is_last;
        if (lane == 0) { rds[w] = ds; ros[w] = os; rmm[w] = mm; }
        __syncthreads();
        if (tid == 0) {
            float DS = rds[0] + rds[1] + rds[2] + rds[3];
            float OS = ros[0] + ros[1] + ros[2] + ros[3];
            float MM = rmm[0] + rmm[1] + rmm[2] + rmm[3];
            const float bd = (float)BB * (float)DD;
            float2 mine;
            mine.x = wgt * MM / bd;
            mine.y = wgt * DS / bd + wgt * OS / (bd * (float)(DD - 1));
            spart[b] = mine;
            __threadfence();                       // release partial
            int old = atomicAdd(fincnt, 1);
            is_last = (old == NBLK - 1);
        }
        __syncthreads();
        if (is_last) {
            __threadfence();                       // acquire all partials
            float2 v = (tid < NBLK) ? spart[tid] : make_float2(0.f, 0.f);
            float a = v.x, bb = v.y;
            #pragma unroll
            for (int off = 32; off > 0; off >>= 1) {
                a  += __shfl_down(a, off);
                bb += __shfl_down(bb, off);
            }
            __shared__ float ra[4], rb[4];
            if (lane == 0) { ra[w] = a; rb[w] = bb; }
            __syncthreads();
            if (tid == 0) {
                outscalars[0] = ra[0] + ra[1] + ra[2] + ra[3];
                outscalars[1] = rb[0] + rb[1] + rb[2] + rb[3];
            }
        }
    }
}

// ---------------------------------------------------------------------------
extern "C" void kernel_launch(void* const* d_in, const int* in_sizes, int n_in,
                              void* d_out, int out_size, void* d_ws, size_t ws_size,
                              hipStream_t stream) {
    const float* x = (const float*)d_in[0];
    const float* centers = (const float*)d_in[1];
    float* out = (float*)d_out;
    float* outscalars = out + (size_t)BB * KK;

    char* ws = (char*)d_ws;
    size_t off = 0;
    float*  part     = (float*)(ws + off); off += (size_t)MAXITEMS * DD * DD * 4; // 8 MB
    float*  emp_part = (float*)(ws + off); off += MAXITEMS * DD * 4;              // 64 KB
    int*    assign   = (int*)  (ws + off); off += BB * 4;                         // 64 KB
    int*    bhist    = (int*)  (ws + off); off += 256 * KK * 4;                   // 64 KB
    float2* spart    = (float2*)(ws + off); off += NBLK * 8;                      // 2 KB
    int*    counters = (int*)  (ws + off); off += 256;

    k_rows<<<256, 256, 0, stream>>>(x, centers, out, assign, bhist, counters);
    k_main<<<NBLK, 256, 0, stream>>>(x, assign, bhist, centers, part, emp_part,
                                     spart, counters, outscalars);
}

// Round 13
// 142.268 us; speedup vs baseline: 1.9294x; 1.9294x over previous
//
#include <hip/hip_runtime.h>

#define BB 16384
#define KK 64
#define DD 128
#define SEG 256          // rows per covariance work-item (2x128-row stages)
#define MAXITEMS 128     // sum_k ceil(cnt_k/SEG) <= 64 + 63 = 127
#define RSLAB 4096       // elements per reduce slab
#define RBLKS 256        // k_redfinal grid = KK x 4

typedef __attribute__((ext_vector_type(8))) short bf16x8;
typedef __attribute__((ext_vector_type(4))) float f32x4;

__device__ __forceinline__ unsigned int packbf2(float a, float b) {
    unsigned ua = __float_as_uint(a);
    unsigned ub = __float_as_uint(b);
    ua = (ua + 0x7FFFu + ((ua >> 16) & 1u)) >> 16;   // RNE f32->bf16
    ub = (ub + 0x7FFFu + ((ub >> 16) & 1u)) >> 16;
    return ua | (ub << 16);
}

// ---------------------------------------------------------------------------
// K1: tiled GEMM. Block = 64 rows x 64 clusters, K=128.
// dist = |x|^2 - 2 x.c + |c|^2 ; |x|^2 cancels in softmax AND argmin.
// Emits per-block cluster histogram bhist[b][k]; zeroes the finish counter.
// ---------------------------------------------------------------------------
__global__ __launch_bounds__(256) void k_rows(
    const float* __restrict__ x, const float* __restrict__ centers,
    float* __restrict__ log_resp, int* __restrict__ assign,
    int* __restrict__ bhist, int* __restrict__ counter)
{
    __shared__ float xs[64][132];    // X tile, +4 pad
    __shared__ float ct[DD][66];     // centers transposed [d][k]
    __shared__ float cn2[KK];
    __shared__ int   lh[KK];

    const int tid = threadIdx.x;
    const int row0 = blockIdx.x * 64;

    if (blockIdx.x == 0 && tid == 0) *counter = 0;
    if (tid < KK) lh[tid] = 0;

    for (int g = tid; g < 64 * 32; g += 256) {
        int r = g >> 5, c4 = g & 31;
        float4 v = ((const float4*)(x + (size_t)(row0 + r) * DD))[c4];
        *(float4*)&xs[r][c4 * 4] = v;
    }
    for (int g = tid; g < KK * 32; g += 256) {
        int k = g >> 5, c4 = g & 31;
        float4 v = ((const float4*)(centers + (size_t)k * DD))[c4];
        ct[c4 * 4 + 0][k] = v.x;
        ct[c4 * 4 + 1][k] = v.y;
        ct[c4 * 4 + 2][k] = v.z;
        ct[c4 * 4 + 3][k] = v.w;
    }
    __syncthreads();
    if (tid < KK) {
        float s = 0.f;
        for (int d = 0; d < DD; ++d) { float c = ct[d][tid]; s = fmaf(c, c, s); }
        cn2[tid] = s;
    }
    __syncthreads();

    const int tr = tid >> 5;
    const int tc = tid & 31;
    const int k0 = tc * 2, k1 = k0 + 1;

    float acc0[8], acc1[8];
    #pragma unroll
    for (int i = 0; i < 8; ++i) { acc0[i] = 0.f; acc1[i] = 0.f; }

    for (int d = 0; d < DD; d += 4) {
        float2 b0 = *(const float2*)&ct[d + 0][k0];
        float2 b1 = *(const float2*)&ct[d + 1][k0];
        float2 b2 = *(const float2*)&ct[d + 2][k0];
        float2 b3 = *(const float2*)&ct[d + 3][k0];
        #pragma unroll
        for (int i = 0; i < 8; ++i) {
            float4 a = *(const float4*)&xs[tr * 8 + i][d];
            acc0[i] = fmaf(a.x, b0.x, acc0[i]);
            acc1[i] = fmaf(a.x, b0.y, acc1[i]);
            acc0[i] = fmaf(a.y, b1.x, acc0[i]);
            acc1[i] = fmaf(a.y, b1.y, acc1[i]);
            acc0[i] = fmaf(a.z, b2.x, acc0[i]);
            acc1[i] = fmaf(a.z, b2.y, acc1[i]);
            acc0[i] = fmaf(a.w, b3.x, acc0[i]);
            acc1[i] = fmaf(a.w, b3.y, acc1[i]);
        }
    }

    const float cn0 = 0.5f * cn2[k0], cn1 = 0.5f * cn2[k1];
    #pragma unroll
    for (int i = 0; i < 8; ++i) {
        int row = row0 + tr * 8 + i;
        float v0 = acc0[i] - cn0;
        float v1 = acc1[i] - cn1;
        float m; int idx;
        if (v1 > v0) { m = v1; idx = k1; } else { m = v0; idx = k0; }
        #pragma unroll
        for (int off = 1; off < 32; off <<= 1) {
            float ov = __shfl_xor(m, off);
            int   oi = __shfl_xor(idx, off);
            if (ov > m || (ov == m && oi < idx)) { m = ov; idx = oi; }
        }
        float s = expf(v0 - m) + expf(v1 - m);
        #pragma unroll
        for (int off = 1; off < 32; off <<= 1) s += __shfl_xor(s, off);
        float ls = logf(s);
        float lr0 = fmaxf(v0 - m - ls, -18.4206807f);  // log(1e-8)
        float lr1 = fmaxf(v1 - m - ls, -18.4206807f);
        *(float2*)&log_resp[(size_t)row * KK + k0] = make_float2(lr0, lr1);
        if (tc == 0) {
            assign[row] = idx;
            atomicAdd(&lh[idx], 1);
        }
    }
    __syncthreads();
    if (tid < KK) bhist[blockIdx.x * KK + tid] = lh[tid];   // coalesced 256B
}

// ---------------------------------------------------------------------------
// K2 (grid 128): each block redundantly derives cluster counts + its own
// item (k, seg) from bhist, gathers its <=256 member rows via ballot-
// compaction scan of assign (R12-verified; no sorted array, no scatter
// kernel), then MFMA Sxx -> part[b] + emp_part[b] non-atomically.
// ---------------------------------------------------------------------------
__global__ __launch_bounds__(256) void k_seg2(
    const float* __restrict__ x, const int* __restrict__ assign,
    const int* __restrict__ bhist,
    float* __restrict__ part, float* __restrict__ emp_part)
{
    __shared__ int ph_tot[4][KK];
    __shared__ int cnt_s[KK];
    __shared__ int wtot[4];
    __shared__ int myk_s, myseg_s;
    __shared__ int rows_s[SEG];
    __shared__ unsigned int XT[DD][68];   // XT[d][j] = bf16 pair rows (2j,2j+1)

    const int tid = threadIdx.x;
    const int b = blockIdx.x;
    const int w = tid >> 6, lane = tid & 63;

    // metadata (redundant per block): counts from bhist, coalesced
    {
        const int t = tid & 63, q = tid >> 6;
        int tot = 0;
        for (int bb = q * 64; bb < q * 64 + 64; ++bb)
            tot += bhist[bb * KK + t];
        ph_tot[q][t] = tot;
    }
    __syncthreads();
    if (tid < KK)
        cnt_s[tid] = ph_tot[0][tid] + ph_tot[1][tid] + ph_tot[2][tid] + ph_tot[3][tid];
    __syncthreads();
    if (tid == 0) {
        int ic = 0;
        myk_s = -1;
        for (int k = 0; k < KK; ++k) {
            int ns = (cnt_s[k] + SEG - 1) / SEG;
            if (b >= ic && b < ic + ns) { myk_s = k; myseg_s = b - ic; }
            ic += ns;
        }
    }
    __syncthreads();
    if (myk_s < 0) return;

    const int kC = myk_s;
    const int lo = myseg_s * SEG;
    const int hi = min(lo + SEG, cnt_s[kC]);
    const int len = hi - lo;

    // gather my rows: ordered ballot-compaction scan of assign
    {
        int running = 0;
        for (int c = 0; c < BB / 256; ++c) {     // 64 chunks of 256 rows
            if (running >= hi) break;            // uniform trip count
            int a = assign[c * 256 + tid];
            bool m = (a == kC);
            unsigned long long bal = __ballot(m);
            if (lane == 0) wtot[w] = __popcll(bal);
            __syncthreads();
            int woff = 0;
            #pragma unroll
            for (int j = 0; j < 4; ++j) if (j < w) woff += wtot[j];
            int ctot = wtot[0] + wtot[1] + wtot[2] + wtot[3];
            if (m) {
                int rank = __popcll(bal & ((1ull << lane) - 1ull));
                int pos = running + woff + rank;
                if (pos >= lo && pos < hi) rows_s[pos - lo] = c * 256 + tid;
            }
            running += ctot;
            __syncthreads();                     // wtot WAR
        }
    }

    const int c4 = lane & 15, q = lane >> 4;
    f32x4 acc[2][8];
    #pragma unroll
    for (int h = 0; h < 2; ++h)
        #pragma unroll
        for (int nt = 0; nt < 8; ++nt)
            acc[h][nt] = (f32x4){0.f, 0.f, 0.f, 0.f};
    float colsum = 0.f;

    for (int half = 0; half < 2; ++half) {
        const int hoff = half * 128;
        const int hlen = min(128, len - hoff);   // uniform across block
        if (hlen <= 0) break;

        __syncthreads();   // WAR on XT (prev half's MFMA reads done)
        // stage: wave w owns dims [w*32, w*32+32); lane owns row pair
        {
            const int r0 = 2 * lane, r1 = 2 * lane + 1;
            const int d0 = w * 32;
            const float* p0 = x + (size_t)rows_s[hoff + (r0 < hlen ? r0 : 0)] * DD + d0;
            const float* p1 = x + (size_t)rows_s[hoff + (r1 < hlen ? r1 : 0)] * DD + d0;
            #pragma unroll
            for (int i = 0; i < 8; ++i) {
                float4 a = make_float4(0.f, 0.f, 0.f, 0.f);
                float4 bb = make_float4(0.f, 0.f, 0.f, 0.f);
                if (r0 < hlen) a  = *(const float4*)(p0 + 4 * i);
                if (r1 < hlen) bb = *(const float4*)(p1 + 4 * i);
                XT[d0 + 4 * i + 0][lane] = packbf2(a.x, bb.x);
                XT[d0 + 4 * i + 1][lane] = packbf2(a.y, bb.y);
                XT[d0 + 4 * i + 2][lane] = packbf2(a.z, bb.z);
                XT[d0 + 4 * i + 3][lane] = packbf2(a.w, bb.w);
            }
        }
        __syncthreads();

        // column sums (f32 from the bf16 data)
        if (tid < DD) {
            float s = 0.f;
            #pragma unroll
            for (int j4 = 0; j4 < 16; ++j4) {
                uint4 v = *(const uint4*)&XT[tid][j4 * 4];
                s += __uint_as_float(v.x << 16) + __uint_as_float(v.x & 0xFFFF0000u);
                s += __uint_as_float(v.y << 16) + __uint_as_float(v.y & 0xFFFF0000u);
                s += __uint_as_float(v.z << 16) + __uint_as_float(v.z & 0xFFFF0000u);
                s += __uint_as_float(v.w << 16) + __uint_as_float(v.w & 0xFFFF0000u);
            }
            colsum += s;
        }

        // MFMA: wave w owns m-tiles {2w, 2w+1} x n-tiles 0..7
        #pragma unroll
        for (int c = 0; c < 4; ++c) {
            const int ku = c * 16 + q * 4;       // u32 index: k0 = c*32 + q*8
            bf16x8 a0 = *(const bf16x8*)&XT[(2 * w + 0) * 16 + c4][ku];
            bf16x8 a1 = *(const bf16x8*)&XT[(2 * w + 1) * 16 + c4][ku];
            #pragma unroll
            for (int nt = 0; nt < 8; ++nt) {
                bf16x8 bb = *(const bf16x8*)&XT[nt * 16 + c4][ku];
                acc[0][nt] = __builtin_amdgcn_mfma_f32_16x16x32_bf16(a0, bb, acc[0][nt], 0, 0, 0);
                acc[1][nt] = __builtin_amdgcn_mfma_f32_16x16x32_bf16(a1, bb, acc[1][nt], 0, 0, 0);
            }
        }
    }

    if (tid < DD) emp_part[b * DD + tid] = colsum;   // non-atomic

    // C/D layout: col = lane&15, row = quad*4 + reg  [m89/m91 verified]
    float* pb = part + (size_t)b * (DD * DD);
    #pragma unroll
    for (int h = 0; h < 2; ++h) {
        const int m0 = (2 * w + h) * 16 + q * 4;
        #pragma unroll
        for (int nt = 0; nt < 8; ++nt) {
            const int n = nt * 16 + c4;
            pb[(m0 + 0) * DD + n] = acc[h][nt].x;
            pb[(m0 + 1) * DD + n] = acc[h][nt].y;
            pb[(m0 + 2) * DD + n] = acc[h][nt].z;
            pb[(m0 + 3) * DD + n] = acc[h][nt].w;
        }
    }
}

// ---------------------------------------------------------------------------
// K3: grid = KK x 4 slabs of 4096 elems. Metadata recomputed from bhist
// (coalesced, redundant). Wave-streaming reduce of item partials (16KB
// contiguous per wave per item, 16 acc chains), emp from emp_part, centered
// covariance, spart + counter + last-block scalar writeout (no same-line
// f32 atomics — R10 lesson).
// ---------------------------------------------------------------------------
__global__ __launch_bounds__(256) void k_redfinal(
    const float* __restrict__ part, const float* __restrict__ emp_part,
    const int* __restrict__ bhist, const float* __restrict__ centers,
    float2* __restrict__ spart, int* __restrict__ counter,
    float* __restrict__ outscalars)
{
    __shared__ int ph_tot[4][KK];
    __shared__ int cnt_s[KK], ist_s[KK], ien_s[KK];
    __shared__ float mu_s[DD], emp_s[DD];
    __shared__ float emp2[2][DD];
    __shared__ float red[4][RSLAB];      // 64 KB

    const int tid = threadIdx.x;
    const int b = blockIdx.x;
    const int kD = b >> 2, p = b & 3;
    const int w = tid >> 6, lane = tid & 63;

    // metadata (redundant): counts + item ranges from bhist
    {
        const int t = tid & 63, q = tid >> 6;
        int tot = 0;
        for (int bb = q * 64; bb < q * 64 + 64; ++bb)
            tot += bhist[bb * KK + t];
        ph_tot[q][t] = tot;
    }
    __syncthreads();
    if (tid < KK)
        cnt_s[tid] = ph_tot[0][tid] + ph_tot[1][tid] + ph_tot[2][tid] + ph_tot[3][tid];
    __syncthreads();
    if (tid == 0) {
        int ic = 0;
        for (int k = 0; k < KK; ++k) {
            ist_s[k] = ic;
            ic += (cnt_s[k] + SEG - 1) / SEG;
            ien_s[k] = ic;
        }
    }
    __syncthreads();

    const int i0 = ist_s[kD], i1 = ien_s[kD];
    const float wgt = (float)cnt_s[kD];
    const float inv = 1.0f / (wgt + 1e-7f);

    // emp = sum over items of emp_part (2 groups x 2 chains = MLP 4)
    {
        const int dh = tid & 127, hf = tid >> 7;
        float e0 = 0.f, e1 = 0.f;
        int it = i0 + hf;
        for (; it + 2 < i1; it += 4) {
            e0 += emp_part[it * DD + dh];
            e1 += emp_part[(it + 2) * DD + dh];
        }
        if (it < i1) e0 += emp_part[it * DD + dh];
        emp2[hf][dh] = e0 + e1;
    }
    __syncthreads();
    if (tid < DD) {
        float e = emp2[0][tid] + emp2[1][tid];
        emp_s[tid] = e;
        mu_s[tid] = e * inv;
    }

    float4 acc[16];
    #pragma unroll
    for (int c = 0; c < 16; ++c) acc[c] = make_float4(0.f, 0.f, 0.f, 0.f);

    const int base = p * RSLAB;
    for (int it = i0 + w; it < i1; it += 4) {
        const float* pb = part + (size_t)it * (DD * DD) + base;
        #pragma unroll
        for (int c = 0; c < 16; ++c) {
            float4 v = *(const float4*)&pb[c * 256 + lane * 4];
            acc[c].x += v.x; acc[c].y += v.y; acc[c].z += v.z; acc[c].w += v.w;
        }
    }
    #pragma unroll
    for (int c = 0; c < 16; ++c)
        *(float4*)&red[w][c * 256 + lane * 4] = acc[c];
    __syncthreads();   // also orders mu_s/emp_s writes

    float ds = 0.f, os = 0.f, mm = 0.f;
    #pragma unroll
    for (int jj = 0; jj < 16; ++jj) {
        int el = jj * 256 + tid;               // stride-1 across lanes
        float sx = red[0][el] + red[1][el] + red[2][el] + red[3][el];
        int gel = base + el;
        int d = gel >> 7, e = gel & 127;
        float ctv = sx - mu_s[d] * emp_s[e] - emp_s[d] * mu_s[e]
                  + wgt * mu_s[d] * mu_s[e];
        float v = ctv * inv;
        if (d == e) { float t = v - 1.f; ds += t * t; }
        else        { os += v * v; }
    }
    if (p == 0 && tid < DD) {
        float t = mu_s[tid] - centers[kD * DD + tid];
        mm = t * t;
    }

    #pragma unroll
    for (int off = 32; off > 0; off >>= 1) {
        ds += __shfl_down(ds, off);
        os += __shfl_down(os, off);
        mm += __shfl_down(mm, off);
    }
    __shared__ float rds[4], ros[4], rmm[4];
    __shared__ int is_last;
    if (lane == 0) { rds[w] = ds; ros[w] = os; rmm[w] = mm; }
    __syncthreads();
    if (tid == 0) {
        float DS = rds[0] + rds[1] + rds[2] + rds[3];
        float OS = ros[0] + ros[1] + ros[2] + ros[3];
        float MM = rmm[0] + rmm[1] + rmm[2] + rmm[3];
        const float bd = (float)BB * (float)DD;
        float2 mine;
        mine.x = wgt * MM / bd;
        mine.y = wgt * DS / bd + wgt * OS / (bd * (float)(DD - 1));
        spart[b] = mine;
        __threadfence();                       // release partial
        int old = atomicAdd(counter, 1);
        is_last = (old == RBLKS - 1);
    }
    __syncthreads();
    if (is_last) {
        __threadfence();                       // acquire all partials
        float2 v = spart[tid];
        float a = v.x, bb = v.y;
        #pragma unroll
        for (int off = 32; off > 0; off >>= 1) {
            a  += __shfl_down(a, off);
            bb += __shfl_down(bb, off);
        }
        __shared__ float ra[4], rb[4];
        if (lane == 0) { ra[w] = a; rb[w] = bb; }
        __syncthreads();
        if (tid == 0) {
            outscalars[0] = ra[0] + ra[1] + ra[2] + ra[3];
            outscalars[1] = rb[0] + rb[1] + rb[2] + rb[3];
        }
    }
}

// ---------------------------------------------------------------------------
extern "C" void kernel_launch(void* const* d_in, const int* in_sizes, int n_in,
                              void* d_out, int out_size, void* d_ws, size_t ws_size,
                              hipStream_t stream) {
    const float* x = (const float*)d_in[0];
    const float* centers = (const float*)d_in[1];
    float* out = (float*)d_out;
    float* outscalars = out + (size_t)BB * KK;

    char* ws = (char*)d_ws;
    size_t off = 0;
    float*  part     = (float*)(ws + off); off += (size_t)MAXITEMS * DD * DD * 4; // 8 MB
    float*  emp_part = (float*)(ws + off); off += MAXITEMS * DD * 4;              // 64 KB
    int*    assign   = (int*)  (ws + off); off += BB * 4;                         // 64 KB
    int*    bhist    = (int*)  (ws + off); off += 256 * KK * 4;                   // 64 KB
    float2* spart    = (float2*)(ws + off); off += RBLKS * 8;                     // 2 KB
    int*    counter  = (int*)  (ws + off); off += 256;

    k_rows    <<<256, 256, 0, stream>>>(x, centers, out, assign, bhist, counter);
    k_seg2    <<<MAXITEMS, 256, 0, stream>>>(x, assign, bhist, part, emp_part);
    k_redfinal<<<RBLKS, 256, 0, stream>>>(part, emp_part, bhist, centers,
                                          spart, counter, outscalars);
}

// Round 14
// 135.256 us; speedup vs baseline: 2.0294x; 1.0518x over previous
//
#include <hip/hip_runtime.h>

#define BB 16384
#define KK 64
#define DD 128
#define SEG 256          // rows per covariance work-item (2x128-row stages)
#define MAXITEMS 128     // sum_k ceil(cnt_k/SEG) <= 64 + 63 = 127
#define RSLAB 4096       // elements per reduce slab
#define RBLKS 256        // k_redfinal grid = KK x 4

typedef __attribute__((ext_vector_type(8))) short bf16x8;
typedef __attribute__((ext_vector_type(4))) float f32x4;

__device__ __forceinline__ unsigned int packbf2(float a, float b) {
    unsigned ua = __float_as_uint(a);
    unsigned ub = __float_as_uint(b);
    ua = (ua + 0x7FFFu + ((ua >> 16) & 1u)) >> 16;   // RNE f32->bf16
    ub = (ub + 0x7FFFu + ((ub >> 16) & 1u)) >> 16;
    return ua | (ub << 16);
}

// ---------------------------------------------------------------------------
// K1: tiled GEMM. Block = 64 rows x 64 clusters, K=128.
// dist = |x|^2 - 2 x.c + |c|^2 ; |x|^2 cancels in softmax AND argmin.
// Emits per-64-row-group cluster histogram bhist[g][k]; zeroes the counter.
// ---------------------------------------------------------------------------
__global__ __launch_bounds__(256) void k_rows(
    const float* __restrict__ x, const float* __restrict__ centers,
    float* __restrict__ log_resp, int* __restrict__ assign,
    int* __restrict__ bhist, int* __restrict__ counter)
{
    __shared__ float xs[64][132];    // X tile, +4 pad
    __shared__ float ct[DD][66];     // centers transposed [d][k]
    __shared__ float cn2[KK];
    __shared__ int   lh[KK];

    const int tid = threadIdx.x;
    const int row0 = blockIdx.x * 64;

    if (blockIdx.x == 0 && tid == 0) *counter = 0;
    if (tid < KK) lh[tid] = 0;

    for (int g = tid; g < 64 * 32; g += 256) {
        int r = g >> 5, c4 = g & 31;
        float4 v = ((const float4*)(x + (size_t)(row0 + r) * DD))[c4];
        *(float4*)&xs[r][c4 * 4] = v;
    }
    for (int g = tid; g < KK * 32; g += 256) {
        int k = g >> 5, c4 = g & 31;
        float4 v = ((const float4*)(centers + (size_t)k * DD))[c4];
        ct[c4 * 4 + 0][k] = v.x;
        ct[c4 * 4 + 1][k] = v.y;
        ct[c4 * 4 + 2][k] = v.z;
        ct[c4 * 4 + 3][k] = v.w;
    }
    __syncthreads();
    if (tid < KK) {
        float s = 0.f;
        for (int d = 0; d < DD; ++d) { float c = ct[d][tid]; s = fmaf(c, c, s); }
        cn2[tid] = s;
    }
    __syncthreads();

    const int tr = tid >> 5;
    const int tc = tid & 31;
    const int k0 = tc * 2, k1 = k0 + 1;

    float acc0[8], acc1[8];
    #pragma unroll
    for (int i = 0; i < 8; ++i) { acc0[i] = 0.f; acc1[i] = 0.f; }

    for (int d = 0; d < DD; d += 4) {
        float2 b0 = *(const float2*)&ct[d + 0][k0];
        float2 b1 = *(const float2*)&ct[d + 1][k0];
        float2 b2 = *(const float2*)&ct[d + 2][k0];
        float2 b3 = *(const float2*)&ct[d + 3][k0];
        #pragma unroll
        for (int i = 0; i < 8; ++i) {
            float4 a = *(const float4*)&xs[tr * 8 + i][d];
            acc0[i] = fmaf(a.x, b0.x, acc0[i]);
            acc1[i] = fmaf(a.x, b0.y, acc1[i]);
            acc0[i] = fmaf(a.y, b1.x, acc0[i]);
            acc1[i] = fmaf(a.y, b1.y, acc1[i]);
            acc0[i] = fmaf(a.z, b2.x, acc0[i]);
            acc1[i] = fmaf(a.z, b2.y, acc1[i]);
            acc0[i] = fmaf(a.w, b3.x, acc0[i]);
            acc1[i] = fmaf(a.w, b3.y, acc1[i]);
        }
    }

    const float cn0 = 0.5f * cn2[k0], cn1 = 0.5f * cn2[k1];
    #pragma unroll
    for (int i = 0; i < 8; ++i) {
        int row = row0 + tr * 8 + i;
        float v0 = acc0[i] - cn0;
        float v1 = acc1[i] - cn1;
        float m; int idx;
        if (v1 > v0) { m = v1; idx = k1; } else { m = v0; idx = k0; }
        #pragma unroll
        for (int off = 1; off < 32; off <<= 1) {
            float ov = __shfl_xor(m, off);
            int   oi = __shfl_xor(idx, off);
            if (ov > m || (ov == m && oi < idx)) { m = ov; idx = oi; }
        }
        float s = expf(v0 - m) + expf(v1 - m);
        #pragma unroll
        for (int off = 1; off < 32; off <<= 1) s += __shfl_xor(s, off);
        float ls = logf(s);
        float lr0 = fmaxf(v0 - m - ls, -18.4206807f);  // log(1e-8)
        float lr1 = fmaxf(v1 - m - ls, -18.4206807f);
        *(float2*)&log_resp[(size_t)row * KK + k0] = make_float2(lr0, lr1);
        if (tc == 0) {
            assign[row] = idx;
            atomicAdd(&lh[idx], 1);
        }
    }
    __syncthreads();
    if (tid < KK) bhist[blockIdx.x * KK + tid] = lh[tid];   // coalesced 256B
}

// ---------------------------------------------------------------------------
// K2 (grid 128): per-block: counts from bhist; per-64-row-group PREFIX of my
// cluster (one 4B load/thread + 8-step LDS scan — no serial global chain;
// R13's serial ballot scan was 48us of dependent round-trips). Each wave then
// gathers only the groups overlapping [lo,hi), positions known a priori from
// the prefix. Then MFMA Sxx -> part[b] + emp_part[b] non-atomically.
// ---------------------------------------------------------------------------
__global__ __launch_bounds__(256) void k_seg2(
    const float* __restrict__ x, const int* __restrict__ assign,
    const int* __restrict__ bhist,
    float* __restrict__ part, float* __restrict__ emp_part)
{
    __shared__ int ph_tot[4][KK];
    __shared__ int cnt_s[KK];
    __shared__ int sc[2][256];
    __shared__ int pre_s[257];
    __shared__ int myk_s, myseg_s;
    __shared__ int rows_s[SEG];
    __shared__ unsigned int XT[DD][68];   // XT[d][j] = bf16 pair rows (2j,2j+1)

    const int tid = threadIdx.x;
    const int b = blockIdx.x;
    const int w = tid >> 6, lane = tid & 63;

    // cluster totals from bhist (coalesced)
    {
        const int t = tid & 63, q = tid >> 6;
        int tot = 0;
        for (int bb = q * 64; bb < q * 64 + 64; ++bb)
            tot += bhist[bb * KK + t];
        ph_tot[q][t] = tot;
    }
    __syncthreads();
    if (tid < KK)
        cnt_s[tid] = ph_tot[0][tid] + ph_tot[1][tid] + ph_tot[2][tid] + ph_tot[3][tid];
    __syncthreads();
    if (tid == 0) {
        int ic = 0;
        myk_s = -1;
        for (int k = 0; k < KK; ++k) {
            int ns = (cnt_s[k] + SEG - 1) / SEG;
            if (b >= ic && b < ic + ns) { myk_s = k; myseg_s = b - ic; }
            ic += ns;
        }
    }
    __syncthreads();
    if (myk_s < 0) return;

    const int kC = myk_s;
    const int lo = myseg_s * SEG;
    const int hi = min(lo + SEG, cnt_s[kC]);
    const int len = hi - lo;

    // per-group prefix of my cluster: pre_s[g] = members in groups < g
    {
        int v = bhist[tid * KK + kC];       // one 4B load/thread, parallel
        sc[0][tid] = v;
        __syncthreads();
        int buf = 0;
        #pragma unroll
        for (int off = 1; off < 256; off <<= 1) {
            int nv = sc[buf][tid];
            if (tid >= off) nv += sc[buf][tid - off];
            sc[buf ^ 1][tid] = nv;
            buf ^= 1;
            __syncthreads();
        }
        if (tid == 0) pre_s[0] = 0;
        pre_s[tid + 1] = sc[buf][tid];      // inclusive -> shifted exclusive
    }
    __syncthreads();

    // gather: wave w handles groups w, w+4, ...; skip (no load) groups
    // outside [lo,hi). Dominant cluster: ~5 groups per block, all parallel.
    for (int g = w; g < 256; g += 4) {
        int p0 = pre_s[g], p1 = pre_s[g + 1];
        if (p1 <= lo || p0 >= hi) continue;         // wave-uniform skip
        int a = assign[g * 64 + lane];
        bool m = (a == kC);
        unsigned long long bal = __ballot(m);
        if (m) {
            int rank = __popcll(bal & ((1ull << lane) - 1ull));
            int pos = p0 + rank;
            if (pos >= lo && pos < hi) rows_s[pos - lo] = g * 64 + lane;
        }
    }
    __syncthreads();

    const int c4 = lane & 15, q = lane >> 4;
    f32x4 acc[2][8];
    #pragma unroll
    for (int h = 0; h < 2; ++h)
        #pragma unroll
        for (int nt = 0; nt < 8; ++nt)
            acc[h][nt] = (f32x4){0.f, 0.f, 0.f, 0.f};
    float colsum = 0.f;

    for (int half = 0; half < 2; ++half) {
        const int hoff = half * 128;
        const int hlen = min(128, len - hoff);   // uniform across block
        if (hlen <= 0) break;

        __syncthreads();   // WAR on XT (prev half's MFMA reads done)
        // stage: wave w owns dims [w*32, w*32+32); lane owns row pair
        {
            const int r0 = 2 * lane, r1 = 2 * lane + 1;
            const int d0 = w * 32;
            const float* p0 = x + (size_t)rows_s[hoff + (r0 < hlen ? r0 : 0)] * DD + d0;
            const float* p1 = x + (size_t)rows_s[hoff + (r1 < hlen ? r1 : 0)] * DD + d0;
            #pragma unroll
            for (int i = 0; i < 8; ++i) {
                float4 a = make_float4(0.f, 0.f, 0.f, 0.f);
                float4 bb = make_float4(0.f, 0.f, 0.f, 0.f);
                if (r0 < hlen) a  = *(const float4*)(p0 + 4 * i);
                if (r1 < hlen) bb = *(const float4*)(p1 + 4 * i);
                XT[d0 + 4 * i + 0][lane] = packbf2(a.x, bb.x);
                XT[d0 + 4 * i + 1][lane] = packbf2(a.y, bb.y);
                XT[d0 + 4 * i + 2][lane] = packbf2(a.z, bb.z);
                XT[d0 + 4 * i + 3][lane] = packbf2(a.w, bb.w);
            }
        }
        __syncthreads();

        // column sums (f32 from the bf16 data)
        if (tid < DD) {
            float s = 0.f;
            #pragma unroll
            for (int j4 = 0; j4 < 16; ++j4) {
                uint4 v = *(const uint4*)&XT[tid][j4 * 4];
                s += __uint_as_float(v.x << 16) + __uint_as_float(v.x & 0xFFFF0000u);
                s += __uint_as_float(v.y << 16) + __uint_as_float(v.y & 0xFFFF0000u);
                s += __uint_as_float(v.z << 16) + __uint_as_float(v.z & 0xFFFF0000u);
                s += __uint_as_float(v.w << 16) + __uint_as_float(v.w & 0xFFFF0000u);
            }
            colsum += s;
        }

        // MFMA: wave w owns m-tiles {2w, 2w+1} x n-tiles 0..7
        #pragma unroll
        for (int c = 0; c < 4; ++c) {
            const int ku = c * 16 + q * 4;       // u32 index: k0 = c*32 + q*8
            bf16x8 a0 = *(const bf16x8*)&XT[(2 * w + 0) * 16 + c4][ku];
            bf16x8 a1 = *(const bf16x8*)&XT[(2 * w + 1) * 16 + c4][ku];
            #pragma unroll
            for (int nt = 0; nt < 8; ++nt) {
                bf16x8 bb = *(const bf16x8*)&XT[nt * 16 + c4][ku];
                acc[0][nt] = __builtin_amdgcn_mfma_f32_16x16x32_bf16(a0, bb, acc[0][nt], 0, 0, 0);
                acc[1][nt] = __builtin_amdgcn_mfma_f32_16x16x32_bf16(a1, bb, acc[1][nt], 0, 0, 0);
            }
        }
    }

    if (tid < DD) emp_part[b * DD + tid] = colsum;   // non-atomic

    // C/D layout: col = lane&15, row = quad*4 + reg  [m89/m91 verified]
    float* pb = part + (size_t)b * (DD * DD);
    #pragma unroll
    for (int h = 0; h < 2; ++h) {
        const int m0 = (2 * w + h) * 16 + q * 4;
        #pragma unroll
        for (int nt = 0; nt < 8; ++nt) {
            const int n = nt * 16 + c4;
            pb[(m0 + 0) * DD + n] = acc[h][nt].x;
            pb[(m0 + 1) * DD + n] = acc[h][nt].y;
            pb[(m0 + 2) * DD + n] = acc[h][nt].z;
            pb[(m0 + 3) * DD + n] = acc[h][nt].w;
        }
    }
}

// ---------------------------------------------------------------------------
// K3: grid = KK x 4 slabs of 4096 elems. Metadata recomputed from bhist.
// Wave-streaming reduce of item partials, emp from emp_part, centered
// covariance, spart + counter + last-block scalar writeout.
// ---------------------------------------------------------------------------
__global__ __launch_bounds__(256) void k_redfinal(
    const float* __restrict__ part, const float* __restrict__ emp_part,
    const int* __restrict__ bhist, const float* __restrict__ centers,
    float2* __restrict__ spart, int* __restrict__ counter,
    float* __restrict__ outscalars)
{
    __shared__ int ph_tot[4][KK];
    __shared__ int cnt_s[KK], ist_s[KK], ien_s[KK];
    __shared__ float mu_s[DD], emp_s[DD];
    __shared__ float emp2[2][DD];
    __shared__ float red[4][RSLAB];      // 64 KB

    const int tid = threadIdx.x;
    const int b = blockIdx.x;
    const int kD = b >> 2, p = b & 3;
    const int w = tid >> 6, lane = tid & 63;

    {
        const int t = tid & 63, q = tid >> 6;
        int tot = 0;
        for (int bb = q * 64; bb < q * 64 + 64; ++bb)
            tot += bhist[bb * KK + t];
        ph_tot[q][t] = tot;
    }
    __syncthreads();
    if (tid < KK)
        cnt_s[tid] = ph_tot[0][tid] + ph_tot[1][tid] + ph_tot[2][tid] + ph_tot[3][tid];
    __syncthreads();
    if (tid == 0) {
        int ic = 0;
        for (int k = 0; k < KK; ++k) {
            ist_s[k] = ic;
            ic += (cnt_s[k] + SEG - 1) / SEG;
            ien_s[k] = ic;
        }
    }
    __syncthreads();

    const int i0 = ist_s[kD], i1 = ien_s[kD];
    const float wgt = (float)cnt_s[kD];
    const float inv = 1.0f / (wgt + 1e-7f);

    // emp = sum over items of emp_part (2 groups x 2 chains = MLP 4)
    {
        const int dh = tid & 127, hf = tid >> 7;
        float e0 = 0.f, e1 = 0.f;
        int it = i0 + hf;
        for (; it + 2 < i1; it += 4) {
            e0 += emp_part[it * DD + dh];
            e1 += emp_part[(it + 2) * DD + dh];
        }
        if (it < i1) e0 += emp_part[it * DD + dh];
        emp2[hf][dh] = e0 + e1;
    }
    __syncthreads();
    if (tid < DD) {
        float e = emp2[0][tid] + emp2[1][tid];
        emp_s[tid] = e;
        mu_s[tid] = e * inv;
    }

    float4 acc[16];
    #pragma unroll
    for (int c = 0; c < 16; ++c) acc[c] = make_float4(0.f, 0.f, 0.f, 0.f);

    const int base = p * RSLAB;
    for (int it = i0 + w; it < i1; it += 4) {
        const float* pb = part + (size_t)it * (DD * DD) + base;
        #pragma unroll
        for (int c = 0; c < 16; ++c) {
            float4 v = *(const float4*)&pb[c * 256 + lane * 4];
            acc[c].x += v.x; acc[c].y += v.y; acc[c].z += v.z; acc[c].w += v.w;
        }
    }
    #pragma unroll
    for (int c = 0; c < 16; ++c)
        *(float4*)&red[w][c * 256 + lane * 4] = acc[c];
    __syncthreads();   // also orders mu_s/emp_s writes

    float ds = 0.f, os = 0.f, mm = 0.f;
    #pragma unroll
    for (int jj = 0; jj < 16; ++jj) {
        int el = jj * 256 + tid;               // stride-1 across lanes
        float sx = red[0][el] + red[1][el] + red[2][el] + red[3][el];
        int gel = base + el;
        int d = gel >> 7, e = gel & 127;
        float ctv = sx - mu_s[d] * emp_s[e] - emp_s[d] * mu_s[e]
                  + wgt * mu_s[d] * mu_s[e];
        float v = ctv * inv;
        if (d == e) { float t = v - 1.f; ds += t * t; }
        else        { os += v * v; }
    }
    if (p == 0 && tid < DD) {
        float t = mu_s[tid] - centers[kD * DD + tid];
        mm = t * t;
    }

    #pragma unroll
    for (int off = 32; off > 0; off >>= 1) {
        ds += __shfl_down(ds, off);
        os += __shfl_down(os, off);
        mm += __shfl_down(mm, off);
    }
    __shared__ float rds[4], ros[4], rmm[4];
    __shared__ int is_last;
    if (lane == 0) { rds[w] = ds; ros[w] = os; rmm[w] = mm; }
    __syncthreads();
    if (tid == 0) {
        float DS = rds[0] + rds[1] + rds[2] + rds[3];
        float OS = ros[0] + ros[1] + ros[2] + ros[3];
        float MM = rmm[0] + rmm[1] + rmm[2] + rmm[3];
        const float bd = (float)BB * (float)DD;
        float2 mine;
        mine.x = wgt * MM / bd;
        mine.y = wgt * DS / bd + wgt * OS / (bd * (float)(DD - 1));
        spart[b] = mine;
        __threadfence();                       // release partial
        int old = atomicAdd(counter, 1);
        is_last = (old == RBLKS - 1);
    }
    __syncthreads();
    if (is_last) {
        __threadfence();                       // acquire all partials
        float2 v = spart[tid];
        float a = v.x, bb = v.y;
        #pragma unroll
        for (int off = 32; off > 0; off >>= 1) {
            a  += __shfl_down(a, off);
            bb += __shfl_down(bb, off);
        }
        __shared__ float ra[4], rb[4];
        if (lane == 0) { ra[w] = a; rb[w] = bb; }
        __syncthreads();
        if (tid == 0) {
            outscalars[0] = ra[0] + ra[1] + ra[2] + ra[3];
            outscalars[1] = rb[0] + rb[1] + rb[2] + rb[3];
        }
    }
}

// ---------------------------------------------------------------------------
extern "C" void kernel_launch(void* const* d_in, const int* in_sizes, int n_in,
                              void* d_out, int out_size, void* d_ws, size_t ws_size,
                              hipStream_t stream) {
    const float* x = (const float*)d_in[0];
    const float* centers = (const float*)d_in[1];
    float* out = (float*)d_out;
    float* outscalars = out + (size_t)BB * KK;

    char* ws = (char*)d_ws;
    size_t off = 0;
    float*  part     = (float*)(ws + off); off += (size_t)MAXITEMS * DD * DD * 4; // 8 MB
    float*  emp_part = (float*)(ws + off); off += MAXITEMS * DD * 4;              // 64 KB
    int*    assign   = (int*)  (ws + off); off += BB * 4;                         // 64 KB
    int*    bhist    = (int*)  (ws + off); off += 256 * KK * 4;                   // 64 KB
    float2* spart    = (float2*)(ws + off); off += RBLKS * 8;                     // 2 KB
    int*    counter  = (int*)  (ws + off); off += 256;

    k_rows    <<<256, 256, 0, stream>>>(x, centers, out, assign, bhist, counter);
    k_seg2    <<<MAXITEMS, 256, 0, stream>>>(x, assign, bhist, part, emp_part);
    k_redfinal<<<RBLKS, 256, 0, stream>>>(part, emp_part, bhist, centers,
                                          spart, counter, outscalars);
}

// Round 15
// 131.636 us; speedup vs baseline: 2.0852x; 1.0275x over previous
//
#include <hip/hip_runtime.h>

#define BB 16384
#define KK 64
#define DD 128
#define GRP 64           // rows per covariance work-item (one 64-row stage)
#define NGRP 256         // 64-row groups in B
#define MAXITEMS 320     // sum_k ceil(cnt_k/64) <= 256 + 63 = 319
#define RSLAB 4096       // elements per reduce slab
#define RBLKS 256        // k_redfinal grid = KK x 4

typedef __attribute__((ext_vector_type(8))) short bf16x8;
typedef __attribute__((ext_vector_type(4))) float f32x4;

__device__ __forceinline__ unsigned int packbf2(float a, float b) {
    unsigned ua = __float_as_uint(a);
    unsigned ub = __float_as_uint(b);
    ua = (ua + 0x7FFFu + ((ua >> 16) & 1u)) >> 16;   // RNE f32->bf16
    ub = (ub + 0x7FFFu + ((ub >> 16) & 1u)) >> 16;
    return ua | (ub << 16);
}

// ---------------------------------------------------------------------------
// K1: tiled GEMM. Block = 64 rows x 64 clusters, K=128.
// dist = |x|^2 - 2 x.c + |c|^2 ; |x|^2 cancels in softmax AND argmin.
// Emits TRANSPOSED histogram bhistT[k][group] (per-cluster rows contiguous).
// ---------------------------------------------------------------------------
__global__ __launch_bounds__(256) void k_rows(
    const float* __restrict__ x, const float* __restrict__ centers,
    float* __restrict__ log_resp, int* __restrict__ assign,
    int* __restrict__ bhistT, int* __restrict__ counter)
{
    __shared__ float xs[64][132];    // X tile, +4 pad
    __shared__ float ct[DD][66];     // centers transposed [d][k]
    __shared__ float cn2[KK];
    __shared__ int   lh[KK];

    const int tid = threadIdx.x;
    const int row0 = blockIdx.x * 64;

    if (blockIdx.x == 0 && tid == 0) *counter = 0;
    if (tid < KK) lh[tid] = 0;

    for (int g = tid; g < 64 * 32; g += 256) {
        int r = g >> 5, c4 = g & 31;
        float4 v = ((const float4*)(x + (size_t)(row0 + r) * DD))[c4];
        *(float4*)&xs[r][c4 * 4] = v;
    }
    for (int g = tid; g < KK * 32; g += 256) {
        int k = g >> 5, c4 = g & 31;
        float4 v = ((const float4*)(centers + (size_t)k * DD))[c4];
        ct[c4 * 4 + 0][k] = v.x;
        ct[c4 * 4 + 1][k] = v.y;
        ct[c4 * 4 + 2][k] = v.z;
        ct[c4 * 4 + 3][k] = v.w;
    }
    __syncthreads();
    if (tid < KK) {
        float s = 0.f;
        for (int d = 0; d < DD; ++d) { float c = ct[d][tid]; s = fmaf(c, c, s); }
        cn2[tid] = s;
    }
    __syncthreads();

    const int tr = tid >> 5;
    const int tc = tid & 31;
    const int k0 = tc * 2, k1 = k0 + 1;

    float acc0[8], acc1[8];
    #pragma unroll
    for (int i = 0; i < 8; ++i) { acc0[i] = 0.f; acc1[i] = 0.f; }

    for (int d = 0; d < DD; d += 4) {
        float2 b0 = *(const float2*)&ct[d + 0][k0];
        float2 b1 = *(const float2*)&ct[d + 1][k0];
        float2 b2 = *(const float2*)&ct[d + 2][k0];
        float2 b3 = *(const float2*)&ct[d + 3][k0];
        #pragma unroll
        for (int i = 0; i < 8; ++i) {
            float4 a = *(const float4*)&xs[tr * 8 + i][d];
            acc0[i] = fmaf(a.x, b0.x, acc0[i]);
            acc1[i] = fmaf(a.x, b0.y, acc1[i]);
            acc0[i] = fmaf(a.y, b1.x, acc0[i]);
            acc1[i] = fmaf(a.y, b1.y, acc1[i]);
            acc0[i] = fmaf(a.z, b2.x, acc0[i]);
            acc1[i] = fmaf(a.z, b2.y, acc1[i]);
            acc0[i] = fmaf(a.w, b3.x, acc0[i]);
            acc1[i] = fmaf(a.w, b3.y, acc1[i]);
        }
    }

    const float cn0 = 0.5f * cn2[k0], cn1 = 0.5f * cn2[k1];
    #pragma unroll
    for (int i = 0; i < 8; ++i) {
        int row = row0 + tr * 8 + i;
        float v0 = acc0[i] - cn0;
        float v1 = acc1[i] - cn1;
        float m; int idx;
        if (v1 > v0) { m = v1; idx = k1; } else { m = v0; idx = k0; }
        #pragma unroll
        for (int off = 1; off < 32; off <<= 1) {
            float ov = __shfl_xor(m, off);
            int   oi = __shfl_xor(idx, off);
            if (ov > m || (ov == m && oi < idx)) { m = ov; idx = oi; }
        }
        float s = expf(v0 - m) + expf(v1 - m);
        #pragma unroll
        for (int off = 1; off < 32; off <<= 1) s += __shfl_xor(s, off);
        float ls = logf(s);
        float lr0 = fmaxf(v0 - m - ls, -18.4206807f);  // log(1e-8)
        float lr1 = fmaxf(v1 - m - ls, -18.4206807f);
        *(float2*)&log_resp[(size_t)row * KK + k0] = make_float2(lr0, lr1);
        if (tc == 0) {
            assign[row] = idx;
            atomicAdd(&lh[idx], 1);
        }
    }
    __syncthreads();
    if (tid < KK) bhistT[tid * NGRP + blockIdx.x] = lh[tid];
}

// ---------------------------------------------------------------------------
// K2 (grid 320): one 64-row item per block. Metadata from bhistT (contiguous
// per cluster), kC group-prefix via one coalesced 1KB load + LDS scan,
// gather via prefix+ballot (R14-verified). Staging is now COALESCED: rows
// read row-major (512B contiguous chunks) into XR, LDS-transposed into XT.
// (R14 lesson: the row-pair-per-lane global gather = 64 lines/instr was the
// latency wall at 1 block/CU.) Then 32 MFMAs -> part[b] + emp_part[b].
// ---------------------------------------------------------------------------
__global__ __launch_bounds__(256) void k_seg2(
    const float* __restrict__ x, const int* __restrict__ assign,
    const int* __restrict__ bhistT,
    float* __restrict__ part, float* __restrict__ emp_part)
{
    __shared__ int ph_tot[4][KK];
    __shared__ int cnt_s[KK];
    __shared__ int sc[2][256];
    __shared__ int pre_s[257];
    __shared__ int myk_s, myseg_s;
    __shared__ int rows_s[GRP];
    __shared__ unsigned int XR[GRP][68];  // row-major: XR[j][dim-pair]
    __shared__ unsigned int XT[DD][36];   // dim-major: XT[d][row-pair], pad 36

    const int tid = threadIdx.x;
    const int b = blockIdx.x;
    const int w = tid >> 6, lane = tid & 63;

    // cluster totals: thread (k = tid&63) sums its contiguous g-range
    {
        const int k = tid & 63, q = tid >> 6;
        const int* p = bhistT + k * NGRP + q * 64;
        int t0 = 0, t1 = 0, t2 = 0, t3 = 0;
        #pragma unroll 4
        for (int i = 0; i < 64; i += 4) {
            t0 += p[i]; t1 += p[i + 1]; t2 += p[i + 2]; t3 += p[i + 3];
        }
        ph_tot[q][k] = t0 + t1 + t2 + t3;
    }
    __syncthreads();
    if (tid < KK)
        cnt_s[tid] = ph_tot[0][tid] + ph_tot[1][tid] + ph_tot[2][tid] + ph_tot[3][tid];
    __syncthreads();
    if (tid == 0) {
        int ic = 0;
        myk_s = -1;
        for (int k = 0; k < KK; ++k) {
            int ns = (cnt_s[k] + GRP - 1) / GRP;
            if (b >= ic && b < ic + ns) { myk_s = k; myseg_s = b - ic; }
            ic += ns;
        }
    }
    __syncthreads();
    if (myk_s < 0) return;

    const int kC = myk_s;
    const int lo = myseg_s * GRP;
    const int hi = min(lo + GRP, cnt_s[kC]);
    const int len = hi - lo;

    // per-group prefix for kC: coalesced 1KB load + Hillis-Steele scan
    {
        int v = bhistT[kC * NGRP + tid];
        sc[0][tid] = v;
        __syncthreads();
        int buf = 0;
        #pragma unroll
        for (int off = 1; off < 256; off <<= 1) {
            int nv = sc[buf][tid];
            if (tid >= off) nv += sc[buf][tid - off];
            sc[buf ^ 1][tid] = nv;
            buf ^= 1;
            __syncthreads();
        }
        if (tid == 0) pre_s[0] = 0;
        pre_s[tid + 1] = sc[buf][tid];
    }
    __syncthreads();

    // gather member row-ids for [lo,hi) (1-2 overlapping groups typically)
    for (int g = w; g < NGRP; g += 4) {
        int p0 = pre_s[g], p1 = pre_s[g + 1];
        if (p1 <= lo || p0 >= hi) continue;          // wave-uniform skip
        int a = assign[g * 64 + lane];
        bool m = (a == kC);
        unsigned long long bal = __ballot(m);
        if (m) {
            int rank = __popcll(bal & ((1ull << lane) - 1ull));
            int pos = p0 + rank;
            if (pos >= lo && pos < hi) rows_s[pos - lo] = g * 64 + lane;
        }
    }
    __syncthreads();

    // stage 1: coalesced row-major read -> XR bf16 (4 sub-iters x 16 rows)
    #pragma unroll
    for (int sub = 0; sub < 4; ++sub) {
        const int j = sub * 16 + (tid >> 4);      // member index [0,64)
        const int c8 = (tid & 15) * 8;            // dim offset
        float4 a = make_float4(0.f, 0.f, 0.f, 0.f);
        float4 c = make_float4(0.f, 0.f, 0.f, 0.f);
        if (j < len) {
            const float* p = x + (size_t)rows_s[j] * DD + c8;
            a = *(const float4*)p;
            c = *(const float4*)(p + 4);
        }
        uint4 pk;
        pk.x = packbf2(a.x, a.y);
        pk.y = packbf2(a.z, a.w);
        pk.z = packbf2(c.x, c.y);
        pk.w = packbf2(c.z, c.w);
        *(uint4*)&XR[j][c8 >> 1] = pk;            // 16B aligned (272B rows)
    }
    __syncthreads();

    // stage 2: LDS transpose XR -> XT (lane: 16 dims x 1 row-pair)
    {
        const int rp = lane & 31;                 // row-pair
        const int d0 = w * 32 + (lane >> 5) * 16; // 16 dims
        const int dp0 = d0 >> 1;                  // 8 dim-pairs
        uint4 a0 = *(const uint4*)&XR[2 * rp][dp0];
        uint4 a1 = *(const uint4*)&XR[2 * rp][dp0 + 4];
        uint4 b0 = *(const uint4*)&XR[2 * rp + 1][dp0];
        uint4 b1 = *(const uint4*)&XR[2 * rp + 1][dp0 + 4];
        unsigned int A[8] = {a0.x, a0.y, a0.z, a0.w, a1.x, a1.y, a1.z, a1.w};
        unsigned int B[8] = {b0.x, b0.y, b0.z, b0.w, b1.x, b1.y, b1.z, b1.w};
        #pragma unroll
        for (int i = 0; i < 8; ++i) {
            XT[d0 + 2 * i + 0][rp] = (A[i] & 0xFFFFu) | (B[i] << 16);
            XT[d0 + 2 * i + 1][rp] = (A[i] >> 16) | (B[i] & 0xFFFF0000u);
        }
    }
    __syncthreads();

    // column sums (f32 from the bf16 data): thread d < 128
    if (tid < DD) {
        float s = 0.f;
        #pragma unroll
        for (int j4 = 0; j4 < 8; ++j4) {
            uint4 v = *(const uint4*)&XT[tid][j4 * 4];
            s += __uint_as_float(v.x << 16) + __uint_as_float(v.x & 0xFFFF0000u);
            s += __uint_as_float(v.y << 16) + __uint_as_float(v.y & 0xFFFF0000u);
            s += __uint_as_float(v.z << 16) + __uint_as_float(v.z & 0xFFFF0000u);
            s += __uint_as_float(v.w << 16) + __uint_as_float(v.w & 0xFFFF0000u);
        }
        emp_part[b * DD + tid] = s;               // non-atomic
    }

    // MFMA: K=64 in 2 chunks of 32 rows; wave w owns m-tiles {2w,2w+1}
    const int c4 = lane & 15, q = lane >> 4;
    f32x4 acc[2][8];
    #pragma unroll
    for (int h = 0; h < 2; ++h)
        #pragma unroll
        for (int nt = 0; nt < 8; ++nt)
            acc[h][nt] = (f32x4){0.f, 0.f, 0.f, 0.f};

    #pragma unroll
    for (int c = 0; c < 2; ++c) {
        const int ku = c * 16 + q * 4;            // u32 idx: k0 = c*32 + q*8
        bf16x8 a0 = *(const bf16x8*)&XT[(2 * w + 0) * 16 + c4][ku];
        bf16x8 a1 = *(const bf16x8*)&XT[(2 * w + 1) * 16 + c4][ku];
        #pragma unroll
        for (int nt = 0; nt < 8; ++nt) {
            bf16x8 bb = *(const bf16x8*)&XT[nt * 16 + c4][ku];
            acc[0][nt] = __builtin_amdgcn_mfma_f32_16x16x32_bf16(a0, bb, acc[0][nt], 0, 0, 0);
            acc[1][nt] = __builtin_amdgcn_mfma_f32_16x16x32_bf16(a1, bb, acc[1][nt], 0, 0, 0);
        }
    }

    // C/D layout: col = lane&15, row = quad*4 + reg  [m89/m91 verified]
    float* pb = part + (size_t)b * (DD * DD);
    #pragma unroll
    for (int h = 0; h < 2; ++h) {
        const int m0 = (2 * w + h) * 16 + q * 4;
        #pragma unroll
        for (int nt = 0; nt < 8; ++nt) {
            const int n = nt * 16 + c4;
            pb[(m0 + 0) * DD + n] = acc[h][nt].x;
            pb[(m0 + 1) * DD + n] = acc[h][nt].y;
            pb[(m0 + 2) * DD + n] = acc[h][nt].z;
            pb[(m0 + 3) * DD + n] = acc[h][nt].w;
        }
    }
}

// ---------------------------------------------------------------------------
// K3: grid = KK x 4 slabs of 4096 elems. Metadata from bhistT. Wave-streaming
// reduce of item partials, emp from emp_part, centered covariance, spart +
// counter + last-block scalar writeout.
// ---------------------------------------------------------------------------
__global__ __launch_bounds__(256) void k_redfinal(
    const float* __restrict__ part, const float* __restrict__ emp_part,
    const int* __restrict__ bhistT, const float* __restrict__ centers,
    float2* __restrict__ spart, int* __restrict__ counter,
    float* __restrict__ outscalars)
{
    __shared__ int ph_tot[4][KK];
    __shared__ int cnt_s[KK], ist_s[KK], ien_s[KK];
    __shared__ float mu_s[DD], emp_s[DD];
    __shared__ float emp2[2][DD];
    __shared__ float red[4][RSLAB];      // 64 KB

    const int tid = threadIdx.x;
    const int b = blockIdx.x;
    const int kD = b >> 2, p = b & 3;
    const int w = tid >> 6, lane = tid & 63;

    {
        const int k = tid & 63, q = tid >> 6;
        const int* pp = bhistT + k * NGRP + q * 64;
        int t0 = 0, t1 = 0, t2 = 0, t3 = 0;
        #pragma unroll 4
        for (int i = 0; i < 64; i += 4) {
            t0 += pp[i]; t1 += pp[i + 1]; t2 += pp[i + 2]; t3 += pp[i + 3];
        }
        ph_tot[q][k] = t0 + t1 + t2 + t3;
    }
    __syncthreads();
    if (tid < KK)
        cnt_s[tid] = ph_tot[0][tid] + ph_tot[1][tid] + ph_tot[2][tid] + ph_tot[3][tid];
    __syncthreads();
    if (tid == 0) {
        int ic = 0;
        for (int k = 0; k < KK; ++k) {
            ist_s[k] = ic;
            ic += (cnt_s[k] + GRP - 1) / GRP;
            ien_s[k] = ic;
        }
    }
    __syncthreads();

    const int i0 = ist_s[kD], i1 = ien_s[kD];
    const float wgt = (float)cnt_s[kD];
    const float inv = 1.0f / (wgt + 1e-7f);

    // emp = sum over items of emp_part (2 groups x 2 chains = MLP 4)
    {
        const int dh = tid & 127, hf = tid >> 7;
        float e0 = 0.f, e1 = 0.f;
        int it = i0 + hf;
        for (; it + 2 < i1; it += 4) {
            e0 += emp_part[it * DD + dh];
            e1 += emp_part[(it + 2) * DD + dh];
        }
        if (it < i1) e0 += emp_part[it * DD + dh];
        emp2[hf][dh] = e0 + e1;
    }
    __syncthreads();
    if (tid < DD) {
        float e = emp2[0][tid] + emp2[1][tid];
        emp_s[tid] = e;
        mu_s[tid] = e * inv;
    }

    float4 acc[16];
    #pragma unroll
    for (int c = 0; c < 16; ++c) acc[c] = make_float4(0.f, 0.f, 0.f, 0.f);

    const int base = p * RSLAB;
    for (int it = i0 + w; it < i1; it += 4) {
        const float* pb = part + (size_t)it * (DD * DD) + base;
        #pragma unroll
        for (int c = 0; c < 16; ++c) {
            float4 v = *(const float4*)&pb[c * 256 + lane * 4];
            acc[c].x += v.x; acc[c].y += v.y; acc[c].z += v.z; acc[c].w += v.w;
        }
    }
    #pragma unroll
    for (int c = 0; c < 16; ++c)
        *(float4*)&red[w][c * 256 + lane * 4] = acc[c];
    __syncthreads();   // also orders mu_s/emp_s writes

    float ds = 0.f, os = 0.f, mm = 0.f;
    #pragma unroll
    for (int jj = 0; jj < 16; ++jj) {
        int el = jj * 256 + tid;               // stride-1 across lanes
        float sx = red[0][el] + red[1][el] + red[2][el] + red[3][el];
        int gel = base + el;
        int d = gel >> 7, e = gel & 127;
        float ctv = sx - mu_s[d] * emp_s[e] - emp_s[d] * mu_s[e]
                  + wgt * mu_s[d] * mu_s[e];
        float v = ctv * inv;
        if (d == e) { float t = v - 1.f; ds += t * t; }
        else        { os += v * v; }
    }
    if (p == 0 && tid < DD) {
        float t = mu_s[tid] - centers[kD * DD + tid];
        mm = t * t;
    }

    #pragma unroll
    for (int off = 32; off > 0; off >>= 1) {
        ds += __shfl_down(ds, off);
        os += __shfl_down(os, off);
        mm += __shfl_down(mm, off);
    }
    __shared__ float rds[4], ros[4], rmm[4];
    __shared__ int is_last;
    if (lane == 0) { rds[w] = ds; ros[w] = os; rmm[w] = mm; }
    __syncthreads();
    if (tid == 0) {
        float DS = rds[0] + rds[1] + rds[2] + rds[3];
        float OS = ros[0] + ros[1] + ros[2] + ros[3];
        float MM = rmm[0] + rmm[1] + rmm[2] + rmm[3];
        const float bd = (float)BB * (float)DD;
        float2 mine;
        mine.x = wgt * MM / bd;
        mine.y = wgt * DS / bd + wgt * OS / (bd * (float)(DD - 1));
        spart[b] = mine;
        __threadfence();                       // release partial
        int old = atomicAdd(counter, 1);
        is_last = (old == RBLKS - 1);
    }
    __syncthreads();
    if (is_last) {
        __threadfence();                       // acquire all partials
        float2 v = spart[tid];
        float a = v.x, bb = v.y;
        #pragma unroll
        for (int off = 32; off > 0; off >>= 1) {
            a  += __shfl_down(a, off);
            bb += __shfl_down(bb, off);
        }
        __shared__ float ra[4], rb[4];
        if (lane == 0) { ra[w] = a; rb[w] = bb; }
        __syncthreads();
        if (tid == 0) {
            outscalars[0] = ra[0] + ra[1] + ra[2] + ra[3];
            outscalars[1] = rb[0] + rb[1] + rb[2] + rb[3];
        }
    }
}

// ---------------------------------------------------------------------------
extern "C" void kernel_launch(void* const* d_in, const int* in_sizes, int n_in,
                              void* d_out, int out_size, void* d_ws, size_t ws_size,
                              hipStream_t stream) {
    const float* x = (const float*)d_in[0];
    const float* centers = (const float*)d_in[1];
    float* out = (float*)d_out;
    float* outscalars = out + (size_t)BB * KK;

    char* ws = (char*)d_ws;
    size_t off = 0;
    float*  part     = (float*)(ws + off); off += (size_t)MAXITEMS * DD * DD * 4; // 21 MB
    float*  emp_part = (float*)(ws + off); off += MAXITEMS * DD * 4;              // 160 KB
    int*    assign   = (int*)  (ws + off); off += BB * 4;                         // 64 KB
    int*    bhistT   = (int*)  (ws + off); off += KK * NGRP * 4;                  // 64 KB
    float2* spart    = (float2*)(ws + off); off += RBLKS * 8;                     // 2 KB
    int*    counter  = (int*)  (ws + off); off += 256;

    k_rows    <<<256, 256, 0, stream>>>(x, centers, out, assign, bhistT, counter);
    k_seg2    <<<MAXITEMS, 256, 0, stream>>>(x, assign, bhistT, part, emp_part);
    k_redfinal<<<RBLKS, 256, 0, stream>>>(part, emp_part, bhistT, centers,
                                          spart, counter, outscalars);
}